// Round 2
// baseline (2015.471 us; speedup 1.0000x reference)
//
#include <hip/hip_runtime.h>
#include <stdint.h>

#define NROWS 16384
#define QNUM  8192
#define ED    512
#define BM    128
#define BN    128
#define BK    64
#define KTILES (ED / BK)   // 8
#define QBLKS  (QNUM / BN) // 64
#define DELTA  0.008f

typedef __bf16 bf16x8 __attribute__((ext_vector_type(8)));
typedef float  f32x4  __attribute__((ext_vector_type(4)));

#define LDS_CAST(p)  ((__attribute__((address_space(3))) void*)(p))
#define GLB_CAST(p)  ((const __attribute__((address_space(1))) void*)(p))

static __device__ __forceinline__ unsigned f2b1(float f) {
    unsigned u = __float_as_uint(f);
    return (u + 0x7FFFu + ((u >> 16) & 1u)) >> 16;   // RNE fp32 -> bf16
}
static __device__ __forceinline__ unsigned f2b2(float lo, float hi) {
    return f2b1(lo) | (f2b1(hi) << 16);
}

// keep top-2 (smallest val, tie -> smallest idx)
static __device__ __forceinline__ void ins2(float& v1, int& q1, float& v2, int& q2,
                                            float s, int q) {
    if (s < v1 || (s == v1 && q < q1)) { v2 = v1; q2 = q1; v1 = s; q1 = q; }
    else if (s < v2 || (s == v2 && q < q2)) { v2 = s; q2 = q; }
}

// ---------------- prep: fp32 -> bf16 (RNE), 8 elems/thread ----------------
__global__ __launch_bounds__(256) void k_prep_bf16(const float* __restrict__ src,
                                                   unsigned* __restrict__ dst) {
    size_t t = (size_t)blockIdx.x * 256 + threadIdx.x;
    const float4* p = (const float4*)(src + t * 8);
    float4 a = p[0], b = p[1];
    uint4 o;
    o.x = f2b2(a.x, a.y); o.y = f2b2(a.z, a.w);
    o.z = f2b2(b.x, b.y); o.w = f2b2(b.z, b.w);
    ((uint4*)dst)[t] = o;
}

// ---------------- numpy-pairwise fp32 sum of squares per 512-row ----------------
// Replicates np.sum(a*a, axis=-1) for fp32 rows of length 512:
//   total = fl(fl(B0+B1) + fl(B2+B3)), each 128-block:
//   r[j] = a[j]^2 + a[j+8]^2 + ... (15 sequential adds), then
//   ((r0+r1)+(r2+r3)) + ((r4+r5)+(r6+r7)).  __f*_rn forbids fma contraction.
#define SROWS 32
#define SSTRIDE 520
__global__ __launch_bounds__(256) void k_sumsq_np(const float* __restrict__ src,
                                                  float* __restrict__ dst) {
    __shared__ float ld[SROWS * SSTRIDE];
    const int t = threadIdx.x;
    const size_t base = (size_t)blockIdx.x * SROWS * ED;
    #pragma unroll
    for (int k = 0; k < 16; ++k) {
        int u = k * 256 + t;          // float4 index within the 32-row slab
        int row = u >> 7;             // 128 float4 per row
        int c4  = u & 127;
        float4 v = ((const float4*)(src + base))[u];
        float* d = ld + row * SSTRIDE + c4 * 4;
        d[0] = v.x; d[1] = v.y; d[2] = v.z; d[3] = v.w;
    }
    __syncthreads();
    const int row = t >> 3, j = t & 7;
    const float* a = ld + row * SSTRIDE;
    float B[4];
    #pragma unroll
    for (int b = 0; b < 4; ++b) {
        const float* p = a + b * 128 + j;
        float r = __fmul_rn(p[0], p[0]);
        #pragma unroll
        for (int i = 1; i < 16; ++i) {
            float q = p[8 * i];
            r = __fadd_rn(r, __fmul_rn(q, q));
        }
        float t1 = __fadd_rn(r,  __shfl_xor(r,  1, 64));
        float t2 = __fadd_rn(t1, __shfl_xor(t1, 2, 64));
        B[b]     = __fadd_rn(t2, __shfl_xor(t2, 4, 64));
    }
    if (j == 0)
        dst[(size_t)blockIdx.x * SROWS + row] =
            __fadd_rn(__fadd_rn(B[0], B[1]), __fadd_rn(B[2], B[3]));
}

// ---------------- phase 1: bf16 MFMA scores + per-(row, 128q-block) top-2 ----------------
__global__ __launch_bounds__(256) void k_gemm_top2(
        const unsigned short* __restrict__ xb,
        const unsigned short* __restrict__ wb,
        const float* __restrict__ wsqf,
        uint4* __restrict__ partial) {
    // XOR-swizzled LDS: granule (16B) for (row, kc) lives at slot row*8 + (kc ^ (row&7)).
    __shared__ unsigned short As[BM * BK];
    __shared__ unsigned short Bs[BN * BK];
    __shared__ uint4 red[2][BM];

    const int t  = threadIdx.x;
    const int wv = t >> 6;
    const int l  = t & 63;
    const int c  = l & 15;   // MFMA col / A-row lane
    const int g  = l >> 4;   // MFMA quad
    const int RB = (wv >> 1) * 64;  // wave row base in block tile
    const int CB = (wv & 1) * 64;   // wave col base
    const int q0 = blockIdx.x * BN;
    const int r0 = blockIdx.y * BM;

    f32x4 acc[4][4];
    #pragma unroll
    for (int i = 0; i < 4; ++i)
        #pragma unroll
        for (int j = 0; j < 4; ++j)
            acc[i][j] = (f32x4){0.f, 0.f, 0.f, 0.f};

    for (int kt = 0; kt < KTILES; ++kt) {
        const int k0 = kt * BK;
        #pragma unroll
        for (int i = 0; i < 4; ++i) {
            const int slot = i * 256 + wv * 64 + l;
            const int row  = slot >> 3;
            const int kc   = (slot & 7) ^ (row & 7);   // inverse swizzle for fetch
            const unsigned short* gA = xb + (size_t)(r0 + row) * ED + k0 + kc * 8;
            __builtin_amdgcn_global_load_lds(GLB_CAST(gA),
                LDS_CAST((char*)As + (size_t)(i * 256 + wv * 64) * 16), 16, 0, 0);
            const unsigned short* gB = wb + (size_t)(q0 + row) * ED + k0 + kc * 8;
            __builtin_amdgcn_global_load_lds(GLB_CAST(gB),
                LDS_CAST((char*)Bs + (size_t)(i * 256 + wv * 64) * 16), 16, 0, 0);
        }
        __syncthreads();
        #pragma unroll
        for (int s = 0; s < 2; ++s) {
            bf16x8 af[4], bfv[4];
            #pragma unroll
            for (int i = 0; i < 4; ++i) {
                const int m  = RB + i * 16 + c;
                const int kc = s * 4 + g;
                af[i] = *(const bf16x8*)(As + m * BK + ((kc ^ (m & 7)) * 8));
            }
            #pragma unroll
            for (int j = 0; j < 4; ++j) {
                const int n  = CB + j * 16 + c;
                const int kc = s * 4 + g;
                bfv[j] = *(const bf16x8*)(Bs + n * BK + ((kc ^ (n & 7)) * 8));
            }
            #pragma unroll
            for (int i = 0; i < 4; ++i)
                #pragma unroll
                for (int j = 0; j < 4; ++j)
                    acc[i][j] = __builtin_amdgcn_mfma_f32_16x16x32_bf16(af[i], bfv[j], acc[i][j], 0, 0, 0);
        }
        __syncthreads();
    }

    // epilogue: score = wsq - 2*dot; top-2 per row over this block's 128 cols
    float v1a[4][4], v2a[4][4];
    int   q1a[4][4], q2a[4][4];
    float wsqv[4];
    #pragma unroll
    for (int j = 0; j < 4; ++j) wsqv[j] = wsqf[q0 + CB + j * 16 + c];

    #pragma unroll
    for (int i = 0; i < 4; ++i) {
        #pragma unroll
        for (int r = 0; r < 4; ++r) {
            float bv1 = 3.4e38f, bv2 = 3.4e38f;
            int   bq1 = 0x7fffffff, bq2 = 0x7fffffff;
            #pragma unroll
            for (int j = 0; j < 4; ++j) {
                const float s = fmaf(-2.0f, acc[i][j][r], wsqv[j]);
                const int   q = q0 + CB + j * 16 + c;
                ins2(bv1, bq1, bv2, bq2, s, q);
            }
            v1a[i][r] = bv1; q1a[i][r] = bq1; v2a[i][r] = bv2; q2a[i][r] = bq2;
        }
    }
    #pragma unroll
    for (int m = 1; m <= 8; m <<= 1) {
        #pragma unroll
        for (int i = 0; i < 4; ++i) {
            #pragma unroll
            for (int r = 0; r < 4; ++r) {
                float ov1 = __shfl_xor(v1a[i][r], m, 64);
                int   oq1 = __shfl_xor(q1a[i][r], m, 64);
                float ov2 = __shfl_xor(v2a[i][r], m, 64);
                int   oq2 = __shfl_xor(q2a[i][r], m, 64);
                ins2(v1a[i][r], q1a[i][r], v2a[i][r], q2a[i][r], ov1, oq1);
                ins2(v1a[i][r], q1a[i][r], v2a[i][r], q2a[i][r], ov2, oq2);
            }
        }
    }
    if (c == 0) {
        #pragma unroll
        for (int i = 0; i < 4; ++i)
            #pragma unroll
            for (int r = 0; r < 4; ++r) {
                const int rl = RB + i * 16 + g * 4 + r;
                red[wv & 1][rl] = make_uint4(__float_as_uint(v1a[i][r]), (unsigned)q1a[i][r],
                                             __float_as_uint(v2a[i][r]), (unsigned)q2a[i][r]);
            }
    }
    __syncthreads();
    if (t < BM) {
        uint4 A = red[0][t], B = red[1][t];
        float av1 = __uint_as_float(A.x), av2 = __uint_as_float(A.z);
        int   aq1 = (int)A.y, aq2 = (int)A.w;
        ins2(av1, aq1, av2, aq2, __uint_as_float(B.x), (int)B.y);
        ins2(av1, aq1, av2, aq2, __uint_as_float(B.z), (int)B.w);
        partial[(size_t)(r0 + t) * QBLKS + blockIdx.x] =
            make_uint4(__float_as_uint(av1), (unsigned)aq1, __float_as_uint(av2), (unsigned)aq2);
    }
}

// ---------------- phase 2: fp32-emulated (numpy semantics) rescore + gather ----------------
__global__ __launch_bounds__(256) void k_rescore(
        const uint4* __restrict__ partial,
        const float* __restrict__ x,
        const float* __restrict__ wt,
        const float* __restrict__ wsqf,
        const float* __restrict__ xsqf,
        float* __restrict__ outq,
        float* __restrict__ outi) {
    const int wv = threadIdx.x >> 6, l = threadIdx.x & 63;
    const int row = blockIdx.x * 4 + wv;

    uint4 p = partial[(size_t)row * QBLKS + l];
    float v1 = __uint_as_float(p.x), v2 = __uint_as_float(p.z);
    int   q1 = (int)p.y, q2 = (int)p.w;

    float gm = v1;
    #pragma unroll
    for (int m = 1; m < 64; m <<= 1) gm = fminf(gm, __shfl_xor(gm, m, 64));
    const float thr = gm + DELTA;

    const float4* xp = (const float4*)(x + (size_t)row * ED + l * 8);
    const float4 xa = xp[0], xbv = xp[1];
    const float xsq = xsqf[row];

    float bestv = 3.4e38f; int bestq = 0x7fffffff;
    unsigned long long mm1 = __ballot(v1 <= thr);
    unsigned long long mm2 = __ballot(v2 <= thr);
    #pragma unroll 1
    for (int slot = 0; slot < 2; ++slot) {
        unsigned long long mm = slot ? mm2 : mm1;
        while (mm) {
            const int ln = __ffsll(mm) - 1;
            mm &= mm - 1;
            const int q = __shfl(slot ? q2 : q1, ln, 64);
            const float4* wp = (const float4*)(wt + (size_t)q * ED + l * 8);
            const float4 wa = wp[0], wbv = wp[1];
            double d = (double)xa.x * wa.x + (double)xa.y * wa.y
                     + (double)xa.z * wa.z + (double)xa.w * wa.w
                     + (double)xbv.x * wbv.x + (double)xbv.y * wbv.y
                     + (double)xbv.z * wbv.z + (double)xbv.w * wbv.w;
            #pragma unroll
            for (int m = 1; m < 64; m <<= 1) d += __shfl_xor(d, m, 64);
            // numpy fp32 semantics: fl32( fl32(x_sq - 2*dot) + w_sq ), first-occurrence argmin
            const float dotf = (float)d;
            const float t1 = __fadd_rn(xsq, __fmul_rn(-2.0f, dotf));
            const float sc = __fadd_rn(t1, wsqf[q]);
            if (sc < bestv || (sc == bestv && q < bestq)) { bestv = sc; bestq = q; }
        }
    }
    const float4* wp = (const float4*)(wt + (size_t)bestq * ED + l * 8);
    float4* op = (float4*)(outq + (size_t)row * ED + l * 8);
    op[0] = wp[0]; op[1] = wp[1];
    if (l == 0) outi[row] = (float)bestq;
}

extern "C" void kernel_launch(void* const* d_in, const int* in_sizes, int n_in,
                              void* d_out, int out_size, void* d_ws, size_t ws_size,
                              hipStream_t stream) {
    (void)in_sizes; (void)n_in; (void)out_size; (void)ws_size;
    const float* x  = (const float*)d_in[0];
    const float* wt = (const float*)d_in[1];

    char* ws = (char*)d_ws;
    unsigned short* xb   = (unsigned short*)ws;               // 16,777,216 B
    unsigned short* wb   = (unsigned short*)(ws + 16777216);  //  8,388,608 B
    float*          wsqf = (float*) (ws + 25165824);          //     32,768 B
    float*          xsqf = (float*) (ws + 25198592);          //     65,536 B
    uint4*          part = (uint4*) (ws + 25264128);          // 16,777,216 B  (total ~40.1 MB)

    float* outq = (float*)d_out;
    float* outi = outq + (size_t)NROWS * ED;

    k_prep_bf16<<<4096, 256, 0, stream>>>(x,  (unsigned*)xb);
    k_prep_bf16<<<2048, 256, 0, stream>>>(wt, (unsigned*)wb);
    k_sumsq_np<<<NROWS / SROWS, 256, 0, stream>>>(x,  xsqf);   // 512 blocks
    k_sumsq_np<<<QNUM  / SROWS, 256, 0, stream>>>(wt, wsqf);   // 256 blocks
    dim3 grid(QBLKS, NROWS / BM);  // 64 x 128
    k_gemm_top2<<<grid, 256, 0, stream>>>(xb, wb, wsqf, part);
    k_rescore<<<4096, 256, 0, stream>>>(part, x, wt, wsqf, xsqf, outq, outi);
}

// Round 3
// 1551.739 us; speedup vs baseline: 1.2988x; 1.2988x over previous
//
#include <hip/hip_runtime.h>
#include <stdint.h>

#define NROWS 16384
#define QNUM  8192
#define ED    512
#define BM    128
#define BN    128
#define BK    64
#define KTILES (ED / BK)   // 8
#define QBLKS  (QNUM / BN) // 64
#define DELTA  0.008f

typedef __bf16 bf16x8 __attribute__((ext_vector_type(8)));
typedef float  f32x4  __attribute__((ext_vector_type(4)));

#define LDS_CAST(p)  ((__attribute__((address_space(3))) void*)(p))
#define GLB_CAST(p)  ((const __attribute__((address_space(1))) void*)(p))

static __device__ __forceinline__ unsigned f2b1(float f) {
    unsigned u = __float_as_uint(f);
    return (u + 0x7FFFu + ((u >> 16) & 1u)) >> 16;   // RNE fp32 -> bf16
}
static __device__ __forceinline__ unsigned f2b2(float lo, float hi) {
    return f2b1(lo) | (f2b1(hi) << 16);
}

// keep top-2 (smallest val, tie -> smallest idx)
static __device__ __forceinline__ void ins2(float& v1, int& q1, float& v2, int& q2,
                                            float s, int q) {
    if (s < v1 || (s == v1 && q < q1)) { v2 = v1; q2 = q1; v1 = s; q1 = q; }
    else if (s < v2 || (s == v2 && q < q2)) { v2 = s; q2 = q; }
}

// ---------------- prep: fp32 -> bf16 (RNE), 8 elems/thread ----------------
__global__ __launch_bounds__(256) void k_prep_bf16(const float* __restrict__ src,
                                                   unsigned* __restrict__ dst) {
    size_t t = (size_t)blockIdx.x * 256 + threadIdx.x;
    const float4* p = (const float4*)(src + t * 8);
    float4 a = p[0], b = p[1];
    uint4 o;
    o.x = f2b2(a.x, a.y); o.y = f2b2(a.z, a.w);
    o.z = f2b2(b.x, b.y); o.w = f2b2(b.z, b.w);
    ((uint4*)dst)[t] = o;
}

// ---------------- numpy-pairwise fp32 sum of squares per 512-row ----------------
#define SROWS 32
#define SSTRIDE 520
__global__ __launch_bounds__(256) void k_sumsq_np(const float* __restrict__ src,
                                                  float* __restrict__ dst) {
    __shared__ float ld[SROWS * SSTRIDE];
    const int t = threadIdx.x;
    const size_t base = (size_t)blockIdx.x * SROWS * ED;
    #pragma unroll
    for (int k = 0; k < 16; ++k) {
        int u = k * 256 + t;          // float4 index within the 32-row slab
        int row = u >> 7;             // 128 float4 per row
        int c4  = u & 127;
        float4 v = ((const float4*)(src + base))[u];
        float* d = ld + row * SSTRIDE + c4 * 4;
        d[0] = v.x; d[1] = v.y; d[2] = v.z; d[3] = v.w;
    }
    __syncthreads();
    const int row = t >> 3, j = t & 7;
    const float* a = ld + row * SSTRIDE;
    float B[4];
    #pragma unroll
    for (int b = 0; b < 4; ++b) {
        const float* p = a + b * 128 + j;
        float r = __fmul_rn(p[0], p[0]);
        #pragma unroll
        for (int i = 1; i < 16; ++i) {
            float q = p[8 * i];
            r = __fadd_rn(r, __fmul_rn(q, q));
        }
        float t1 = __fadd_rn(r,  __shfl_xor(r,  1, 64));
        float t2 = __fadd_rn(t1, __shfl_xor(t1, 2, 64));
        B[b]     = __fadd_rn(t2, __shfl_xor(t2, 4, 64));
    }
    if (j == 0)
        dst[(size_t)blockIdx.x * SROWS + row] =
            __fadd_rn(__fadd_rn(B[0], B[1]), __fadd_rn(B[2], B[3]));
}

// ---------------- phase 1: bf16 MFMA scores + per-(row, 128q-block) top-2 ----------------
__global__ __launch_bounds__(256) void k_gemm_top2(
        const unsigned short* __restrict__ xb,
        const unsigned short* __restrict__ wb,
        const float* __restrict__ wsqf,
        uint4* __restrict__ partial) {
    // XOR-swizzled LDS: granule (16B) for (row, kc) lives at slot row*8 + (kc ^ (row&7)).
    __shared__ unsigned short As[BM * BK];
    __shared__ unsigned short Bs[BN * BK];
    __shared__ uint4 red[2][BM];

    const int t  = threadIdx.x;
    const int wv = t >> 6;
    const int l  = t & 63;
    const int c  = l & 15;   // MFMA col / A-row lane
    const int g  = l >> 4;   // MFMA quad
    const int RB = (wv >> 1) * 64;  // wave row base in block tile
    const int CB = (wv & 1) * 64;   // wave col base
    const int q0 = blockIdx.x * BN;
    const int r0 = blockIdx.y * BM;

    f32x4 acc[4][4];
    #pragma unroll
    for (int i = 0; i < 4; ++i)
        #pragma unroll
        for (int j = 0; j < 4; ++j)
            acc[i][j] = (f32x4){0.f, 0.f, 0.f, 0.f};

    for (int kt = 0; kt < KTILES; ++kt) {
        const int k0 = kt * BK;
        #pragma unroll
        for (int i = 0; i < 4; ++i) {
            const int slot = i * 256 + wv * 64 + l;
            const int row  = slot >> 3;
            const int kc   = (slot & 7) ^ (row & 7);   // inverse swizzle for fetch
            const unsigned short* gA = xb + (size_t)(r0 + row) * ED + k0 + kc * 8;
            __builtin_amdgcn_global_load_lds(GLB_CAST(gA),
                LDS_CAST((char*)As + (size_t)(i * 256 + wv * 64) * 16), 16, 0, 0);
            const unsigned short* gB = wb + (size_t)(q0 + row) * ED + k0 + kc * 8;
            __builtin_amdgcn_global_load_lds(GLB_CAST(gB),
                LDS_CAST((char*)Bs + (size_t)(i * 256 + wv * 64) * 16), 16, 0, 0);
        }
        __syncthreads();
        #pragma unroll
        for (int s = 0; s < 2; ++s) {
            bf16x8 af[4], bfv[4];
            #pragma unroll
            for (int i = 0; i < 4; ++i) {
                const int m  = RB + i * 16 + c;
                const int kc = s * 4 + g;
                af[i] = *(const bf16x8*)(As + m * BK + ((kc ^ (m & 7)) * 8));
            }
            #pragma unroll
            for (int j = 0; j < 4; ++j) {
                const int n  = CB + j * 16 + c;
                const int kc = s * 4 + g;
                bfv[j] = *(const bf16x8*)(Bs + n * BK + ((kc ^ (n & 7)) * 8));
            }
            #pragma unroll
            for (int i = 0; i < 4; ++i)
                #pragma unroll
                for (int j = 0; j < 4; ++j)
                    acc[i][j] = __builtin_amdgcn_mfma_f32_16x16x32_bf16(af[i], bfv[j], acc[i][j], 0, 0, 0);
        }
        __syncthreads();
    }

    // epilogue (fused, low-liveness): for each owned row, local top-2 over 4 col
    // groups, 16-lane butterfly, immediate LDS write. Max live state ~16 scalars
    // (+ acc), vs the previous 128-value arrays that spilled to scratch and
    // generated 2.6 GB of writes/dispatch.
    float wsqv[4];
    #pragma unroll
    for (int j = 0; j < 4; ++j) wsqv[j] = wsqf[q0 + CB + j * 16 + c];

    #pragma unroll
    for (int i = 0; i < 4; ++i) {
        #pragma unroll
        for (int r = 0; r < 4; ++r) {
            float bv1 = 3.4e38f, bv2 = 3.4e38f;
            int   bq1 = 0x7fffffff, bq2 = 0x7fffffff;
            #pragma unroll
            for (int j = 0; j < 4; ++j) {
                const float s = fmaf(-2.0f, acc[i][j][r], wsqv[j]);
                const int   q = q0 + CB + j * 16 + c;
                ins2(bv1, bq1, bv2, bq2, s, q);
            }
            #pragma unroll
            for (int m = 1; m <= 8; m <<= 1) {
                float ov1 = __shfl_xor(bv1, m, 64);
                int   oq1 = __shfl_xor(bq1, m, 64);
                float ov2 = __shfl_xor(bv2, m, 64);
                int   oq2 = __shfl_xor(bq2, m, 64);
                ins2(bv1, bq1, bv2, bq2, ov1, oq1);
                ins2(bv1, bq1, bv2, bq2, ov2, oq2);
            }
            if (c == 0) {
                const int rl = RB + i * 16 + g * 4 + r;
                red[wv & 1][rl] = make_uint4(__float_as_uint(bv1), (unsigned)bq1,
                                             __float_as_uint(bv2), (unsigned)bq2);
            }
        }
    }
    __syncthreads();
    if (t < BM) {
        uint4 A = red[0][t], B = red[1][t];
        float av1 = __uint_as_float(A.x), av2 = __uint_as_float(A.z);
        int   aq1 = (int)A.y, aq2 = (int)A.w;
        ins2(av1, aq1, av2, aq2, __uint_as_float(B.x), (int)B.y);
        ins2(av1, aq1, av2, aq2, __uint_as_float(B.z), (int)B.w);
        partial[(size_t)(r0 + t) * QBLKS + blockIdx.x] =
            make_uint4(__float_as_uint(av1), (unsigned)aq1, __float_as_uint(av2), (unsigned)aq2);
    }
}

// ---------------- phase 2: fp32-emulated (numpy semantics) rescore + gather ----------------
__global__ __launch_bounds__(256) void k_rescore(
        const uint4* __restrict__ partial,
        const float* __restrict__ x,
        const float* __restrict__ wt,
        const float* __restrict__ wsqf,
        const float* __restrict__ xsqf,
        float* __restrict__ outq,
        float* __restrict__ outi) {
    const int wv = threadIdx.x >> 6, l = threadIdx.x & 63;
    const int row = blockIdx.x * 4 + wv;

    uint4 p = partial[(size_t)row * QBLKS + l];
    float v1 = __uint_as_float(p.x), v2 = __uint_as_float(p.z);
    int   q1 = (int)p.y, q2 = (int)p.w;

    float gm = v1;
    #pragma unroll
    for (int m = 1; m < 64; m <<= 1) gm = fminf(gm, __shfl_xor(gm, m, 64));
    const float thr = gm + DELTA;

    const float4* xp = (const float4*)(x + (size_t)row * ED + l * 8);
    const float4 xa = xp[0], xbv = xp[1];
    const float xsq = xsqf[row];

    float bestv = 3.4e38f; int bestq = 0x7fffffff;
    unsigned long long mm1 = __ballot(v1 <= thr);
    unsigned long long mm2 = __ballot(v2 <= thr);
    #pragma unroll 1
    for (int slot = 0; slot < 2; ++slot) {
        unsigned long long mm = slot ? mm2 : mm1;
        while (mm) {
            const int ln = __ffsll(mm) - 1;
            mm &= mm - 1;
            const int q = __shfl(slot ? q2 : q1, ln, 64);
            const float4* wp = (const float4*)(wt + (size_t)q * ED + l * 8);
            const float4 wa = wp[0], wbv = wp[1];
            double d = (double)xa.x * wa.x + (double)xa.y * wa.y
                     + (double)xa.z * wa.z + (double)xa.w * wa.w
                     + (double)xbv.x * wbv.x + (double)xbv.y * wbv.y
                     + (double)xbv.z * wbv.z + (double)xbv.w * wbv.w;
            #pragma unroll
            for (int m = 1; m < 64; m <<= 1) d += __shfl_xor(d, m, 64);
            // numpy fp32 semantics: fl32( fl32(x_sq - 2*dot) + w_sq ), first-occurrence argmin
            const float dotf = (float)d;
            const float t1 = __fadd_rn(xsq, __fmul_rn(-2.0f, dotf));
            const float sc = __fadd_rn(t1, wsqf[q]);
            if (sc < bestv || (sc == bestv && q < bestq)) { bestv = sc; bestq = q; }
        }
    }
    const float4* wp = (const float4*)(wt + (size_t)bestq * ED + l * 8);
    float4* op = (float4*)(outq + (size_t)row * ED + l * 8);
    op[0] = wp[0]; op[1] = wp[1];
    if (l == 0) outi[row] = (float)bestq;
}

extern "C" void kernel_launch(void* const* d_in, const int* in_sizes, int n_in,
                              void* d_out, int out_size, void* d_ws, size_t ws_size,
                              hipStream_t stream) {
    (void)in_sizes; (void)n_in; (void)out_size; (void)ws_size;
    const float* x  = (const float*)d_in[0];
    const float* wt = (const float*)d_in[1];

    char* ws = (char*)d_ws;
    unsigned short* xb   = (unsigned short*)ws;               // 16,777,216 B
    unsigned short* wb   = (unsigned short*)(ws + 16777216);  //  8,388,608 B
    float*          wsqf = (float*) (ws + 25165824);          //     32,768 B
    float*          xsqf = (float*) (ws + 25198592);          //     65,536 B
    uint4*          part = (uint4*) (ws + 25264128);          // 16,777,216 B  (total ~40.1 MB)

    float* outq = (float*)d_out;
    float* outi = outq + (size_t)NROWS * ED;

    k_prep_bf16<<<4096, 256, 0, stream>>>(x,  (unsigned*)xb);
    k_prep_bf16<<<2048, 256, 0, stream>>>(wt, (unsigned*)wb);
    k_sumsq_np<<<NROWS / SROWS, 256, 0, stream>>>(x,  xsqf);   // 512 blocks
    k_sumsq_np<<<QNUM  / SROWS, 256, 0, stream>>>(wt, wsqf);   // 256 blocks
    dim3 grid(QBLKS, NROWS / BM);  // 64 x 128
    k_gemm_top2<<<grid, 256, 0, stream>>>(xb, wb, wsqf, part);
    k_rescore<<<4096, 256, 0, stream>>>(part, x, wt, wsqf, xsqf, outq, outi);
}